// Round 1
// baseline (1465.283 us; speedup 1.0000x reference)
//
#include <hip/hip_runtime.h>

// 2-layer LSTM (H=32, D=10, T=512) fused into one kernel.
// One thread per gate (128 threads per batch element), NB=2 batches/block.
// Weights register-resident; h/c state + gate transpose via LDS; the block's
// x slice (40KB) staged to LDS once so the sequential T-loop does no global IO.

#define HH 32
#define DD 10
#define TT 512
#define NB 2
#define NTHR (NB * 128)

__device__ __forceinline__ float fast_sigmoid(float v) {
    float e = __expf(-v);
    return __builtin_amdgcn_rcpf(1.0f + e);
}
__device__ __forceinline__ float fast_tanh(float v) {
    return fmaf(2.0f, fast_sigmoid(2.0f * v), -1.0f);
}

__global__ __launch_bounds__(NTHR) void lstm2_fused(
    const float* __restrict__ x,
    const float* __restrict__ Wih0, const float* __restrict__ Whh0,
    const float* __restrict__ bih0, const float* __restrict__ bhh0,
    const float* __restrict__ Wih1, const float* __restrict__ Whh1,
    const float* __restrict__ bih1, const float* __restrict__ bhh1,
    const float* __restrict__ Wfc,  const float* __restrict__ bfc,
    float* __restrict__ out, int B)
{
    __shared__ __align__(16) float xs[NB][TT * DD];   // 40960 B
    __shared__ __align__(16) float h1s[NB][HH];
    __shared__ __align__(16) float h2s[NB][HH];
    __shared__ __align__(16) float gates[NB][4 * HH];

    const int tid = threadIdx.x;
    const int nb  = tid >> 7;        // batch within block
    const int g   = tid & 127;       // gate index 0..127
    const int b0  = blockIdx.x * NB;

    // ---- stage this block's x slice into LDS (coalesced float4) ----
    {
        const float4* src = (const float4*)(x + (size_t)b0 * TT * DD);
        float4* dst = (float4*)&xs[0][0];
        for (int i = tid; i < NB * TT * DD / 4; i += NTHR) dst[i] = src[i];
    }

    // ---- per-thread weights in registers (fully unrolled => no scratch) ----
    float wx[DD], w0[HH], wi1[HH], wh1[HH];
#pragma unroll
    for (int d = 0; d < DD; d++) wx[d] = Wih0[g * DD + d];
#pragma unroll
    for (int k = 0; k < HH; k++) w0[k]  = Whh0[g * HH + k];
#pragma unroll
    for (int k = 0; k < HH; k++) wi1[k] = Wih1[g * HH + k];
#pragma unroll
    for (int k = 0; k < HH; k++) wh1[k] = Whh1[g * HH + k];
    const float bb0 = bih0[g] + bhh0[g];
    const float bb1 = bih1[g] + bhh1[g];

    // gate slot [64,96) is tanh, others sigmoid: act = sB*sigmoid(sA*x)+sC
    const bool is_t = (g >= 64) && (g < 96);
    const float sA = is_t ? 2.0f : 1.0f;
    const float sB = is_t ? 2.0f : 1.0f;
    const float sC = is_t ? -1.0f : 0.0f;

    float c1 = 0.0f, c2 = 0.0f;
    if (g < HH) { h1s[nb][g] = 0.0f; h2s[nb][g] = 0.0f; }
    __syncthreads();

    for (int t = 0; t < TT; t++) {
        // ---------- phase A: layer-1 gate pre-activations ----------
        float acc = bb0;
        {
            const float* xp = &xs[nb][t * DD];
#pragma unroll
            for (int d = 0; d < DD; d += 2) {
                float2 v = *(const float2*)(xp + d);   // 8B-aligned (t*40B)
                acc = fmaf(wx[d],     v.x, acc);
                acc = fmaf(wx[d + 1], v.y, acc);
            }
        }
#pragma unroll
        for (int j = 0; j < HH / 4; j++) {
            float4 hv = *(const float4*)&h1s[nb][4 * j];   // wave-uniform bcast
            acc = fmaf(w0[4 * j + 0], hv.x, acc);
            acc = fmaf(w0[4 * j + 1], hv.y, acc);
            acc = fmaf(w0[4 * j + 2], hv.z, acc);
            acc = fmaf(w0[4 * j + 3], hv.w, acc);
        }
        gates[nb][g] = fmaf(sB, fast_sigmoid(sA * acc), sC);
        __syncthreads();

        // ---------- phase B: layer-1 cell/hidden update ----------
        if (g < HH) {
            float iv = gates[nb][g];
            float fv = gates[nb][g + 32];
            float gv = gates[nb][g + 64];
            float ov = gates[nb][g + 96];
            c1 = fmaf(fv, c1, iv * gv);
            h1s[nb][g] = ov * fast_tanh(c1);
        }
        __syncthreads();

        // ---------- phase C: layer-2 gate pre-activations ----------
        float acc2 = bb1;
#pragma unroll
        for (int j = 0; j < HH / 4; j++) {
            float4 hv = *(const float4*)&h1s[nb][4 * j];
            acc2 = fmaf(wi1[4 * j + 0], hv.x, acc2);
            acc2 = fmaf(wi1[4 * j + 1], hv.y, acc2);
            acc2 = fmaf(wi1[4 * j + 2], hv.z, acc2);
            acc2 = fmaf(wi1[4 * j + 3], hv.w, acc2);
        }
#pragma unroll
        for (int j = 0; j < HH / 4; j++) {
            float4 hv = *(const float4*)&h2s[nb][4 * j];
            acc2 = fmaf(wh1[4 * j + 0], hv.x, acc2);
            acc2 = fmaf(wh1[4 * j + 1], hv.y, acc2);
            acc2 = fmaf(wh1[4 * j + 2], hv.z, acc2);
            acc2 = fmaf(wh1[4 * j + 3], hv.w, acc2);
        }
        gates[nb][g] = fmaf(sB, fast_sigmoid(sA * acc2), sC);
        __syncthreads();

        // ---------- phase D: layer-2 cell/hidden update ----------
        if (g < HH) {
            float iv = gates[nb][g];
            float fv = gates[nb][g + 32];
            float gv = gates[nb][g + 64];
            float ov = gates[nb][g + 96];
            c2 = fmaf(fv, c2, iv * gv);
            h2s[nb][g] = ov * fast_tanh(c2);
        }
        __syncthreads();
    }

    // ---------- final FC on last h2 ----------
    if (g == 0) {
        int b = b0 + nb;
        if (b < B) {
            float v = bfc[0];
#pragma unroll
            for (int k = 0; k < HH; k++) v = fmaf(h2s[nb][k], Wfc[k], v);
            out[b] = v;
        }
    }
}

extern "C" void kernel_launch(void* const* d_in, const int* in_sizes, int n_in,
                              void* d_out, int out_size, void* d_ws, size_t ws_size,
                              hipStream_t stream) {
    const float* x    = (const float*)d_in[0];
    const float* Wih0 = (const float*)d_in[1];
    const float* Whh0 = (const float*)d_in[2];
    const float* bih0 = (const float*)d_in[3];
    const float* bhh0 = (const float*)d_in[4];
    const float* Wih1 = (const float*)d_in[5];
    const float* Whh1 = (const float*)d_in[6];
    const float* bih1 = (const float*)d_in[7];
    const float* bhh1 = (const float*)d_in[8];
    const float* Wfc  = (const float*)d_in[9];
    const float* bfc  = (const float*)d_in[10];
    float* out = (float*)d_out;

    const int B = in_sizes[0] / (TT * DD);   // 4096
    dim3 grid(B / NB), block(NTHR);
    hipLaunchKernelGGL(lstm2_fused, grid, block, 0, stream,
                       x, Wih0, Whh0, bih0, bhh0,
                       Wih1, Whh1, bih1, bhh1, Wfc, bfc, out, B);
}

// Round 2
// 1184.442 us; speedup vs baseline: 1.2371x; 1.2371x over previous
//
#include <hip/hip_runtime.h>

// 2-layer LSTM (H=32, D=10, T=512), layer-pipelined:
// threads   0..127: layer-1 gate (unit j = t>>2, gate q = t&3) for timestep k
// threads 128..255: layer-2 gate for timestep k-1  (software wavefront)
// Weights register-resident (42 or 64 floats/thread). All 4 gates of a unit
// live in adjacent lanes -> gate exchange is an intra-wave LDS write +
// float4 broadcast read (no barrier). One __syncthreads() per iteration.
// h1/h2 double-buffered in LDS by timestep parity.

#define HH 32
#define DD 10
#define TT 512

__device__ __forceinline__ float fast_sigmoid(float v) {
    float e = __expf(-v);
    return __builtin_amdgcn_rcpf(1.0f + e);
}
__device__ __forceinline__ float fast_tanh(float v) {
    return fmaf(2.0f, fast_sigmoid(2.0f * v), -1.0f);
}

__global__ __launch_bounds__(256, 4) void lstm2_pipe(
    const float* __restrict__ x,
    const float* __restrict__ Wih0, const float* __restrict__ Whh0,
    const float* __restrict__ bih0, const float* __restrict__ bhh0,
    const float* __restrict__ Wih1, const float* __restrict__ Whh1,
    const float* __restrict__ bih1, const float* __restrict__ bhh1,
    const float* __restrict__ Wfc,  const float* __restrict__ bfc,
    float* __restrict__ out)
{
    __shared__ __align__(16) float xs[TT * DD];     // 20480 B, this batch's x
    __shared__ __align__(16) float h1buf[2][HH];    // double-buffered by parity
    __shared__ __align__(16) float h2buf[2][HH];
    __shared__ __align__(16) float gl[256];         // intra-wave gate exchange

    const int tid  = threadIdx.x;
    const bool isL1 = tid < 128;
    const int tl   = tid & 127;
    const int j    = tl >> 2;          // hidden unit
    const int q    = tl & 3;           // gate role: 0=i 1=f 2=g(tanh) 3=o
    const int row  = q * HH + j;       // weight row in original layout

    // ---- stage this batch's x into LDS (coalesced float4) ----
    {
        const float4* src = (const float4*)(x + (size_t)blockIdx.x * TT * DD);
        float4* dst = (float4*)xs;
        #pragma unroll
        for (int i = 0; i < 5; i++) dst[tid + 256 * i] = src[tid + 256 * i];
    }

    // ---- register-resident weights ----
    float wA[HH], wB[HH];
    float bb;
    if (isL1) {
        #pragma unroll
        for (int d = 0; d < DD; d++) wA[d] = Wih0[row * DD + d];   // x proj
        #pragma unroll
        for (int m = 0; m < HH; m++) wB[m] = Whh0[row * HH + m];   // h1 recur
        bb = bih0[row] + bhh0[row];
    } else {
        #pragma unroll
        for (int m = 0; m < HH; m++) wA[m] = Whh1[row * HH + m];   // h2 recur
        #pragma unroll
        for (int m = 0; m < HH; m++) wB[m] = Wih1[row * HH + m];   // h1 input
        bb = bih1[row] + bhh1[row];
    }

    // activation selector: act(x) = sB * sigmoid(sA*x) + sC  (tanh for q==2)
    const bool is_t = (q == 2);
    const float sA = is_t ? 2.0f : 1.0f;
    const float sB = is_t ? 2.0f : 1.0f;
    const float sC = is_t ? -1.0f : 0.0f;

    // zero h state (both parities)
    if (tid < 64)       (&h1buf[0][0])[tid]      = 0.0f;
    else if (tid < 128) (&h2buf[0][0])[tid - 64] = 0.0f;

    float c = 0.0f;
    __syncthreads();

    for (int k = 0; k <= TT; ++k) {
        const int pr = k & 1;
        const bool active = isL1 ? (k < TT) : (k > 0);
        float a;
        if (isL1) {
            if (k < TT) {
                float acc = bb;
                const float* xp = &xs[k * DD];
                #pragma unroll
                for (int d = 0; d < DD; d += 2) {
                    float2 v = *(const float2*)(xp + d);     // 8B aligned
                    acc = fmaf(wA[d],     v.x, acc);
                    acc = fmaf(wA[d + 1], v.y, acc);
                }
                const float* hp = &h1buf[pr ^ 1][0];         // h1(k-1)
                #pragma unroll
                for (int m = 0; m < HH; m += 4) {
                    float4 hv = *(const float4*)(hp + m);    // uniform bcast
                    acc = fmaf(wB[m + 0], hv.x, acc);
                    acc = fmaf(wB[m + 1], hv.y, acc);
                    acc = fmaf(wB[m + 2], hv.z, acc);
                    acc = fmaf(wB[m + 3], hv.w, acc);
                }
                a = fmaf(sB, fast_sigmoid(sA * acc), sC);
            }
        } else {
            if (k > 0) {
                float acc = bb;
                const float* h1p = &h1buf[pr ^ 1][0];        // h1(k-1) input
                const float* h2p = &h2buf[pr][0];            // h2(k-2) recur
                #pragma unroll
                for (int m = 0; m < HH; m += 4) {
                    float4 hv = *(const float4*)(h1p + m);
                    acc = fmaf(wB[m + 0], hv.x, acc);
                    acc = fmaf(wB[m + 1], hv.y, acc);
                    acc = fmaf(wB[m + 2], hv.z, acc);
                    acc = fmaf(wB[m + 3], hv.w, acc);
                }
                #pragma unroll
                for (int m = 0; m < HH; m += 4) {
                    float4 hv = *(const float4*)(h2p + m);
                    acc = fmaf(wA[m + 0], hv.x, acc);
                    acc = fmaf(wA[m + 1], hv.y, acc);
                    acc = fmaf(wA[m + 2], hv.z, acc);
                    acc = fmaf(wA[m + 3], hv.w, acc);
                }
                a = fmaf(sB, fast_sigmoid(sA * acc), sC);
            }
        }

        if (active) {
            gl[tid] = a;
            asm volatile("" ::: "memory");   // order intra-wave LDS write->read
            float4 gv = *(const float4*)&gl[tid & ~3];  // i,f,g~,o (activated)
            c = fmaf(gv.y, c, gv.x * gv.z);
            float h = gv.w * fast_tanh(c);
            if (q == 0) {
                if (isL1) h1buf[pr][j]     = h;   // h1(k)   @ parity k&1
                else      h2buf[pr ^ 1][j] = h;   // h2(k-1) @ parity (k-1)&1
            }
        }
        __syncthreads();
    }

    // ---- final FC on h2(T-1): parity (T-1)&1 == 1 ----
    if (tid == 0) {
        float v = bfc[0];
        #pragma unroll
        for (int m = 0; m < HH; ++m) v = fmaf(h2buf[1][m], Wfc[m], v);
        out[blockIdx.x] = v;
    }
}

extern "C" void kernel_launch(void* const* d_in, const int* in_sizes, int n_in,
                              void* d_out, int out_size, void* d_ws, size_t ws_size,
                              hipStream_t stream) {
    const float* x    = (const float*)d_in[0];
    const float* Wih0 = (const float*)d_in[1];
    const float* Whh0 = (const float*)d_in[2];
    const float* bih0 = (const float*)d_in[3];
    const float* bhh0 = (const float*)d_in[4];
    const float* Wih1 = (const float*)d_in[5];
    const float* Whh1 = (const float*)d_in[6];
    const float* bih1 = (const float*)d_in[7];
    const float* bhh1 = (const float*)d_in[8];
    const float* Wfc  = (const float*)d_in[9];
    const float* bfc  = (const float*)d_in[10];
    float* out = (float*)d_out;

    const int B = in_sizes[0] / (TT * DD);   // 4096
    dim3 grid(B), block(256);
    hipLaunchKernelGGL(lstm2_pipe, grid, block, 0, stream,
                       x, Wih0, Whh0, bih0, bhh0,
                       Wih1, Whh1, bih1, bhh1, Wfc, bfc, out);
}